// Round 6
// baseline (766.750 us; speedup 1.0000x reference)
//
#include <hip/hip_runtime.h>
#include <hip/hip_bf16.h>
#include <math.h>

typedef __bf16 bf16_t;
typedef __bf16 bf16x8 __attribute__((ext_vector_type(8)));
typedef __bf16 bf16x4 __attribute__((ext_vector_type(4)));
typedef float floatx4 __attribute__((ext_vector_type(4)));

#define BATCH 65536L
#define ROWS 64
#define MFMA __builtin_amdgcn_mfma_f32_16x16x32_bf16

// ---------------- helpers ----------------

__device__ __forceinline__ float softplus_f(float x) {
  const float l = __logf(1.f + __expf(x));
  return (x > 15.f) ? x : l;
}
__device__ __forceinline__ float sigmoid_f(float x) {
  return __builtin_amdgcn_rcpf(1.f + __expf(-x));
}

// fragment-linear activation store/load: element block (row=mf*16+lr, cols c0..c0+3)
__device__ __forceinline__ void store_frag(char* buf, int NKT, int mf, int c0, int lr, bf16x4 v) {
  const int kt = c0 >> 5, lkp = (c0 & 31) >> 3, j0 = c0 & 7;
  *(bf16x4*)(buf + (((mf * NKT + kt) * 64) + lr + 16 * lkp) * 16 + j0 * 2) = v;
}
__device__ __forceinline__ bf16x4 load_frag(const char* buf, int NKT, int mf, int c0, int lr) {
  const int kt = c0 >> 5, lkp = (c0 & 31) >> 3, j0 = c0 & 7;
  return *(const bf16x4*)(buf + (((mf * NKT + kt) * 64) + lr + 16 * lkp) * 16 + j0 * 2);
}

// ---------------- ring-pipelined frag-linear GEMM (R22-verified, KS split) -------
// Weights kt-major: [kt][NT][lane][8]. A from LDS: [mf][KTL][lane][8].
// R23: same rolled 4-stage weight ring as R22 (measured clean at 88 VGPR),
// generalized with KTL (A layout stride) vs KS (kt rows processed) for the
// GEMM4 K-split across wave pairs. The perf lever this round is NOT in here --
// it's 16 waves (4/SIMD) for cross-wave pipe overlap; see kernel comment.

template<int MF, int KTL, int KS, int NT, int NF>
__device__ __forceinline__ void gemmP(const char* Abuf, const bf16_t* W, int ntb,
                                      int lane, floatx4 (&acc)[MF][NF])
{
  static_assert(KS % 4 == 0, "KS must be a multiple of the ring period");
  const char* wp = (const char*)W + (ntb * 64 + lane) * 16;
  const char* ap = Abuf + lane * 16;
  bf16x8 bv[4][NF];   // weight ring, 4 stages (prefetch distance 3)
  bf16x8 av[2][MF];   // A ping-pong (distance 1)
#pragma unroll
  for (int st = 0; st < 3; ++st)
#pragma unroll
    for (int nf = 0; nf < NF; ++nf)
      bv[st][nf] = *(const bf16x8*)(wp + (st * NT + nf) * 1024);
#pragma unroll
  for (int m = 0; m < MF; ++m)
    av[0][m] = *(const bf16x8*)(ap + m * KTL * 1024);
#pragma unroll 1
  for (int b = 0; b < KS / 4; ++b) {
#pragma unroll
    for (int c = 0; c < 4; ++c) {
      // A for cluster c+1 (distance 1; last body's c=3 reads 1KB past A -- LDS-safe)
#pragma unroll
      for (int m = 0; m < MF; ++m)
        av[(c + 1) & 1][m] = *(const bf16x8*)(ap + ((c + 1) + m * KTL) * 1024);
      // weights for cluster c+3 (distance 3; tail reads land in padded slack)
#pragma unroll
      for (int nf = 0; nf < NF; ++nf)
        bv[(c + 3) & 3][nf] = *(const bf16x8*)(wp + ((c + 3) * NT + nf) * 1024);
      __builtin_amdgcn_s_setprio(1);
#pragma unroll
      for (int m = 0; m < MF; ++m)
#pragma unroll
        for (int nf = 0; nf < NF; ++nf)
          acc[m][nf] = MFMA(bv[c & 3][nf], av[c & 1][m], acc[m][nf], 0, 0, 0);
      __builtin_amdgcn_s_setprio(0);
    }
    wp += 4 * NT * 1024;
    ap += 4 * 1024;
  }
}

// GEMM1: K=192 = zf_dyn (NKT=4) + zstat (NKT=2); weights NT=32, KT=6; kt pairs
// (0,1),(2,3) read zf; (4,5) read zst. MF=4, NF=2, single pass (16 waves).
__device__ __forceinline__ void gemm_g1(const char* zf, const char* zs, const bf16_t* W,
                                        int ntb, int lane, floatx4 (&acc)[4][2])
{
  const char* wp = (const char*)W + (ntb * 64 + lane) * 16;
  bf16x8 bv0[2], bv1[2];
#pragma unroll
  for (int nf = 0; nf < 2; ++nf) bv0[nf] = *(const bf16x8*)(wp + nf * 1024);
#pragma unroll 1
  for (int kt = 0; kt < 6; kt += 2) {
    const char* ab = (kt < 4) ? (zf + kt * 1024 + lane * 16)
                              : (zs + (kt - 4) * 1024 + lane * 16);
    const int  ms = (kt < 4) ? 4096 : 2048;   // mf stride (NKT*1024)
#pragma unroll
    for (int nf = 0; nf < 2; ++nf)
      bv1[nf] = *(const bf16x8*)(wp + 32 * 1024 + nf * 1024);
    bf16x8 a[4];
#pragma unroll
    for (int m = 0; m < 4; ++m) a[m] = *(const bf16x8*)(ab + m * ms);
    __builtin_amdgcn_s_setprio(1);
#pragma unroll
    for (int m = 0; m < 4; ++m)
#pragma unroll
      for (int nf = 0; nf < 2; ++nf)
        acc[m][nf] = MFMA(bv0[nf], a[m], acc[m][nf], 0, 0, 0);
    __builtin_amdgcn_s_setprio(0);
    if (kt + 2 < 6) {
#pragma unroll
      for (int nf = 0; nf < 2; ++nf)
        bv0[nf] = *(const bf16x8*)(wp + 64 * 1024 + nf * 1024);
    }
#pragma unroll
    for (int m = 0; m < 4; ++m) a[m] = *(const bf16x8*)(ab + 1024 + m * ms);
    __builtin_amdgcn_s_setprio(1);
#pragma unroll
    for (int m = 0; m < 4; ++m)
#pragma unroll
      for (int nf = 0; nf < 2; ++nf)
        acc[m][nf] = MFMA(bv1[nf], a[m], acc[m][nf], 0, 0, 0);
    __builtin_amdgcn_s_setprio(0);
    wp += 64 * 1024;
  }
}

// ------- fused kernel: 64 rows/block, 16 waves (1024 thr), 1 block/CU -----------
// R23 theory: the measured step wall ~= MFMA(26k cy) + L2(24k) + VALU(11k)
// SERIALIZED -- 2 waves/SIMD in barrier lockstep can't overlap the pipes.
// 16 waves = 4/SIMD gives cross-wave overlap (one wave's epilogue VALU under
// another's MFMA clusters) with UNCHANGED per-CU L2 weight traffic (each
// wave owns a disjoint nt slice). R19 proved the structure correct but died
// to __launch_bounds__(1024,4)'s 64-VGPR cap; plain __launch_bounds__(1024)
// caps at 128 (fit 16 waves) and the single-pass NF=2 shape needs ~90.
// yt epilogue moved to a separate tiny kernel (was serial, conflict-heavy).

__global__ __launch_bounds__(1024)
void ham_fused(const float* __restrict__ z_dyn, const float* __restrict__ z_static,
               const float* __restrict__ dtp, const float* __restrict__ ut,
               const float* __restrict__ b1, const float* __restrict__ b2,
               const bf16_t* __restrict__ W1s, const bf16_t* __restrict__ W2s,
               const bf16_t* __restrict__ W2ts, const bf16_t* __restrict__ W1ts,
               const float* __restrict__ Bc,
               float* __restrict__ z_out)
{
  __shared__ __align__(16) char bufX[65536];   // h1 -> g1 (NKT=16, mf 0..3)
  __shared__ __align__(16) char bufY[65536];   // zf (NKT=4, 0..16K) -> g2 (NKT=16); G4 partials @+16K
  __shared__ __align__(16) char zst[8192];     // z_static frags (NKT=2, mf 0..3)
  __shared__ __align__(16) float uBs[64 * 68]; // uB, padded stride 68

  const int tid  = threadIdx.x;
  const int lane = tid & 63;
  const int w    = tid >> 6;      // 0..15
  const int lr   = lane & 15;
  const int lk   = lane >> 4;     // 0..3
  const long rb  = (long)blockIdx.x * ROWS;

  // dt is wave-uniform: pin to SGPR
  const float dtv = __builtin_bit_cast(float,
      __builtin_amdgcn_readfirstlane(__builtin_bit_cast(int, dtp[0])));
  const float hstep = dtv * 0.25f;
  const int   pcb   = ((w + 4) & 7) * 16;   // partner col base for z layout (waves 0..7)

  // ---- init: Bc -> bufX (f32), z_static -> zst (frag-linear bf16), zp regs
  for (int e = tid; e < 64 * 16; e += 1024) ((float*)bufX)[e] = Bc[e];
  for (int e = tid; e < ROWS * 64; e += 1024) {
    const int rr = e >> 6, cc = e & 63;
    const float v = __builtin_nontemporal_load(z_static + (rb + rr) * 64 + cc);
    const int kt = cc >> 5, lkp = (cc & 31) >> 3, j = cc & 7;
    *(bf16_t*)(zst + ((((rr >> 4) * 2 + kt) * 64) + (rr & 15) + 16 * lkp) * 16 + j * 2) = (bf16_t)v;
  }
  floatx4 zp[4];
  if (w < 8) {
#pragma unroll
    for (int m = 0; m < 4; ++m)
      zp[m] = __builtin_nontemporal_load(
          (const floatx4*)(z_dyn + (rb + m * 16 + lr) * 128 + pcb + lk * 4));
  }
  __syncthreads();

  // ---- uB -> LDS (reads Bc from bufX; bufX reused after B1)
  for (int e = tid; e < ROWS * 64; e += 1024) {
    const int rr = e >> 6, cc = e & 63;
    const float* ur = ut + (rb + rr) * 16;
    const float* bc = (const float*)bufX + cc * 16;
    float s = 0.f;
#pragma unroll
    for (int u = 0; u < 16; ++u) s += ur[u] * bc[u];
    uBs[rr * 68 + cc] = s;
  }

  for (int s = 0; s < 4; ++s) {
    // ---- pack zf (bufY, NKT=4) from z regs (waves 0..7: all 4 row-frags, own cols)
    if (w < 8) {
#pragma unroll
      for (int m = 0; m < 4; ++m) {
        bf16x4 o;
#pragma unroll
        for (int i = 0; i < 4; ++i) o[i] = (bf16_t)zp[m][i];
        store_frag(bufY, 4, m, pcb + lk * 4, lr, o);
      }
    }
    __syncthreads();   // B1: zf+uBs ready; everyone past GEMM4 bufX/partial reads

    // ---- GEMM1 -> h1 (bufX), single pass: wave w owns cols w*32..w*32+31
    {
      floatx4 acc[4][2] = {};
      gemm_g1(bufY, zst, W1s, w * 2, lane, acc);
#pragma unroll
      for (int m = 0; m < 4; ++m)
#pragma unroll
        for (int nf = 0; nf < 2; ++nf) {
          const int c0 = w * 32 + nf * 16 + lk * 4;
          const floatx4 b4 = *(const floatx4*)(b1 + c0);
          bf16x4 h4;
#pragma unroll
          for (int i = 0; i < 4; ++i) h4[i] = (bf16_t)softplus_f(acc[m][nf][i] + b4[i]);
          store_frag(bufX, 16, m, c0, lr, h4);
        }
    }
    __syncthreads();   // B2: h1 ready

    // ---- GEMM2 -> g2 = sigmoid(a2+b2) (bufY), single pass  [w3 folded into W2ts]
    {
      floatx4 acc[4][2] = {};
      gemmP<4, 16, 16, 32, 2>(bufX, W2s, w * 2, lane, acc);
#pragma unroll
      for (int m = 0; m < 4; ++m)
#pragma unroll
        for (int nf = 0; nf < 2; ++nf) {
          const int c0 = w * 32 + nf * 16 + lk * 4;
          const floatx4 b4 = *(const floatx4*)(b2 + c0);
          bf16x4 g4;
#pragma unroll
          for (int i = 0; i < 4; ++i) g4[i] = (bf16_t)sigmoid_f(acc[m][nf][i] + b4[i]);
          store_frag(bufY, 16, m, c0, lr, g4);
        }
    }
    __syncthreads();   // B3: g2 ready

    // ---- GEMM3 -> g1 = s1 * (g2 @ (w3.W2)) (bufX), single pass
    {
      floatx4 acc[4][2] = {};
      gemmP<4, 16, 16, 32, 2>(bufY, W2ts, w * 2, lane, acc);
#pragma unroll
      for (int m = 0; m < 4; ++m)
#pragma unroll
        for (int nf = 0; nf < 2; ++nf) {
          const int c0 = w * 32 + nf * 16 + lk * 4;
          const bf16x4 h4 = load_frag(bufX, 16, m, c0, lr);   // lane-private bytes
          bf16x4 g4;
#pragma unroll
          for (int i = 0; i < 4; ++i) {
            const float s1 = 1.f - __expf(-(float)h4[i]);     // sigmoid(a1) from h1
            g4[i] = (bf16_t)(s1 * acc[m][nf][i]);
          }
          store_frag(bufX, 16, m, c0, lr, g4);
        }
    }
    __syncthreads();   // B4: g1 ready

    // ---- GEMM4 (K-split over wave pairs): dH col block (w&7)*16, kt half w>>3
    {
      floatx4 a4[4][1] = {};
      const int nt4 = w & 7, kh = w >> 3;
      gemmP<4, 16, 8, 8, 1>(bufX + kh * 8192, W1ts + kh * 32768, nt4, lane, a4);
      float* pb = (float*)(bufY + 16384);   // zf region (0..16K) untouched; g2 dead after B4
      if (kh) {
#pragma unroll
        for (int m = 0; m < 4; ++m)
          *(floatx4*)(pb + (m * 16 + lr) * 132 + nt4 * 16 + lk * 4) = a4[m][0];
      }
      __syncthreads(); // B5: partials ready
      if (!kh) {
#pragma unroll
        for (int m = 0; m < 4; ++m) {
          const floatx4 pp = *(const floatx4*)(pb + (m * 16 + lr) * 132 + nt4 * 16 + lk * 4);
          if (w < 4) {
            const float* ub = &uBs[(m * 16 + lr) * 68 + w * 16 + lk * 4];
#pragma unroll
            for (int i = 0; i < 4; ++i) zp[m][i] += hstep * (ub[i] - (a4[m][0][i] + pp[i]));
          } else {
#pragma unroll
            for (int i = 0; i < 4; ++i) zp[m][i] += hstep * (a4[m][0][i] + pp[i]);
          }
        }
      }
    }
    // next B1 separates GEMM4 bufX/partial reads from next-step writes
  }

  // ---- final z store (nontemporal); yt handled by yt_kernel
  if (w < 8) {
#pragma unroll
    for (int m = 0; m < 4; ++m)
      __builtin_nontemporal_store(zp[m],
          (floatx4*)(z_out + (rb + m * 16 + lr) * 128 + pcb + lk * 4));
  }
}

// ---------------- yt kernel: yt = z @ C^T + dt * (ut @ D^T) ----------------------
// One thread per batch row. C staged in LDS and read BROADCAST (all lanes same
// address per iteration -- conflict-free), z streamed as floatx4.

__global__ __launch_bounds__(256)
void yt_kernel(const float* __restrict__ z, const float* __restrict__ ut,
               const float* __restrict__ Cm, const float* __restrict__ Dm,
               const float* __restrict__ dtp, float* __restrict__ yt_out)
{
  __shared__ float Cs[20 * 128];
  __shared__ float Ds[20 * 16];
  const int tid = threadIdx.x;
  for (int e = tid; e < 20 * 128; e += 256) Cs[e] = Cm[e];
  for (int e = tid; e < 20 * 16; e += 256) Ds[e] = Dm[e];
  const float dtv = dtp[0];
  __syncthreads();

  const long r = (long)blockIdx.x * 256 + tid;
  const float* zr = z + r * 128;
  float acc[20] = {};
#pragma unroll 4
  for (int i = 0; i < 128; i += 4) {
    const floatx4 zv = *(const floatx4*)(zr + i);
#pragma unroll
    for (int o = 0; o < 20; ++o) {
      const floatx4 cv = *(const floatx4*)(Cs + o * 128 + i);
      acc[o] += zv[0] * cv[0] + zv[1] * cv[1] + zv[2] * cv[2] + zv[3] * cv[3];
    }
  }
  float uv[16];
#pragma unroll
  for (int u = 0; u < 16; u += 4)
    *(floatx4*)(uv + u) = *(const floatx4*)(ut + r * 16 + u);
#pragma unroll
  for (int o = 0; o < 20; ++o) {
    float su = 0.f;
#pragma unroll
    for (int u = 0; u < 16; ++u) su += uv[u] * Ds[o * 16 + u];
    __builtin_nontemporal_store(acc[o] + dtv * su, yt_out + r * 20 + o);
  }
}

// ---------------- prep: kt-major fragment-linear shuffled weights ----------------
// shuf[((kt*NT + nt)*64 + ln)*8 + j] = Bt[nt*16 + (ln&15)][kt*32 + (ln>>4)*8 + j]

__global__ void prep_shuffle(const float* W1, const float* W2, const float* W3,
                             bf16_t* W1s, bf16_t* W2s, bf16_t* W2ts, bf16_t* W1ts)
{
  const long idx = (long)blockIdx.x * 256 + threadIdx.x;
  const long S1 = 98304, S2 = 262144, S3 = 262144, S4 = 65536;
  if (idx < S1) {                                   // Bt = W1 (512 x 192), NT=32, KT=6
    const long e = idx;
    const int j = (int)(e & 7), ln = (int)((e >> 3) & 63), tile = (int)(e >> 9);
    const int nt = tile & 31, kt = tile >> 5;
    const int srow = nt * 16 + (ln & 15), scol = kt * 32 + (ln >> 4) * 8 + j;
    W1s[e] = (bf16_t)W1[srow * 192 + scol];
  } else if (idx < S1 + S2) {                       // Bt = W2 (512 x 512), NT=32, KT=16
    const long e = idx - S1;
    const int j = (int)(e & 7), ln = (int)((e >> 3) & 63), tile = (int)(e >> 9);
    const int nt = tile & 31, kt = tile >> 5;
    const int srow = nt * 16 + (ln & 15), scol = kt * 32 + (ln >> 4) * 8 + j;
    W2s[e] = (bf16_t)W2[srow * 512 + scol];
  } else if (idx < S1 + S2 + S3) {                  // Bt[j][k] = W2[k][j]*w3[k], NT=32, KT=16
    const long e = idx - S1 - S2;
    const int j = (int)(e & 7), ln = (int)((e >> 3) & 63), tile = (int)(e >> 9);
    const int nt = tile & 31, kt = tile >> 5;
    const int srow = nt * 16 + (ln & 15), scol = kt * 32 + (ln >> 4) * 8 + j;
    W2ts[e] = (bf16_t)(W2[scol * 512 + srow] * W3[scol]);
  } else if (idx < S1 + S2 + S3 + S4) {             // Bt[j][k] = W1[k][j], j<128, NT=8, KT=16
    const long e = idx - S1 - S2 - S3;
    const int j = (int)(e & 7), ln = (int)((e >> 3) & 63), tile = (int)(e >> 9);
    const int nt = tile & 7, kt = tile >> 3;
    const int srow = nt * 16 + (ln & 15), scol = kt * 32 + (ln >> 4) * 8 + j;
    W1ts[e] = (bf16_t)W1[scol * 192 + srow];
  }
}

// ---------------- launch ----------------

extern "C" void kernel_launch(void* const* d_in, const int* in_sizes, int n_in,
                              void* d_out, int out_size, void* d_ws, size_t ws_size,
                              hipStream_t stream)
{
  const float* z_dyn    = (const float*)d_in[0];
  const float* z_static = (const float*)d_in[1];
  const float* dtp      = (const float*)d_in[2];
  const float* ut       = (const float*)d_in[3];
  const float* W1       = (const float*)d_in[4];
  const float* b1       = (const float*)d_in[5];
  const float* W2       = (const float*)d_in[6];
  const float* b2       = (const float*)d_in[7];
  const float* W3       = (const float*)d_in[8];
  const float* Bc       = (const float*)d_in[10];
  const float* Cm       = (const float*)d_in[11];
  const float* Dm       = (const float*)d_in[12];

  float* z_out  = (float*)d_out;            // B x 128
  float* yt_out = z_out + BATCH * 128;      // B x 20

  char* ws = (char*)d_ws;
  size_t off = 0;
  auto alloc = [&](size_t bytes) {
    char* p = ws + off;
    off = (off + bytes + 255) & ~(size_t)255;
    return p;
  };
  bf16_t* W1s  = (bf16_t*)alloc(98304 * 2);
  bf16_t* W2s  = (bf16_t*)alloc(262144 * 2);
  bf16_t* W2ts = (bf16_t*)alloc(262144 * 2);
  // +32KB slack: ring prefetch (distance 3) reads up to 3 clusters past the
  // logical end of W1ts (incl. the kh=1 K-split half); keep reads in-bounds.
  bf16_t* W1ts = (bf16_t*)alloc(65536 * 2 + 32768);
  (void)ws_size; (void)in_sizes; (void)n_in; (void)out_size;

  prep_shuffle<<<2688, 256, 0, stream>>>(W1, W2, W3, W1s, W2s, W2ts, W1ts);
  ham_fused<<<(int)(BATCH / ROWS), 1024, 0, stream>>>(
      z_dyn, z_static, dtp, ut, b1, b2, W1s, W2s, W2ts, W1ts, Bc, z_out);
  yt_kernel<<<(int)(BATCH / 256), 256, 0, stream>>>(z_out, ut, Cm, Dm, dtp, yt_out);
}

// Round 7
// 547.938 us; speedup vs baseline: 1.3993x; 1.3993x over previous
//
#include <hip/hip_runtime.h>
#include <hip/hip_bf16.h>
#include <math.h>

typedef __bf16 bf16_t;
typedef __bf16 bf16x8 __attribute__((ext_vector_type(8)));
typedef __bf16 bf16x4 __attribute__((ext_vector_type(4)));
typedef float floatx4 __attribute__((ext_vector_type(4)));

#define BATCH 65536L
#define ROWS 32
#define MFMA __builtin_amdgcn_mfma_f32_16x16x32_bf16

// ---------------- helpers ----------------

__device__ __forceinline__ float softplus_f(float x) {
  const float l = __logf(1.f + __expf(x));
  return (x > 15.f) ? x : l;
}
__device__ __forceinline__ float sigmoid_f(float x) {
  return __builtin_amdgcn_rcpf(1.f + __expf(-x));
}

// fragment-linear activation store/load: element block (row=mf*16+lr, cols c0..c0+3)
__device__ __forceinline__ void store_frag(char* buf, int NKT, int mf, int c0, int lr, bf16x4 v) {
  const int kt = c0 >> 5, lkp = (c0 & 31) >> 3, j0 = c0 & 7;
  *(bf16x4*)(buf + (((mf * NKT + kt) * 64) + lr + 16 * lkp) * 16 + j0 * 2) = v;
}
__device__ __forceinline__ bf16x4 load_frag(const char* buf, int NKT, int mf, int c0, int lr) {
  const int kt = c0 >> 5, lkp = (c0 & 31) >> 3, j0 = c0 & 7;
  return *(const bf16x4*)(buf + (((mf * NKT + kt) * 64) + lr + 16 * lkp) * 16 + j0 * 2);
}

// ---------------- ring-pipelined frag-linear GEMM (R22-verified) -----------------
// Weights kt-major: [kt][NT][lane][8]. A from LDS: [mf][KTL][lane][8].
// R24: 32-ROW blocks, 2 blocks/CU. R19/R23's 16-wave single block died 3x to
// the compiler's arch-VGPR cap (64 at 4 waves/SIMD assumed); 2 independent
// 8-wave blocks give the SAME 4 waves/SIMD TLP (cross-block MFMA/VALU/L2
// overlap -- blocks are phase-free w.r.t. each other) while per-wave state
// halves (MF=2) to ~90 regs, safe under the proven (512,2)->128 cap.
// Per-CU MFMA count and LDS traffic are unchanged; weight streams are
// per-block (worst case 2x L2 traffic = 48k cy < the current 67k serial wall).

template<int MF, int KTL, int KS, int NT, int NF>
__device__ __forceinline__ void gemmP(const char* Abuf, const bf16_t* W, int ntb,
                                      int lane, floatx4 (&acc)[MF][NF])
{
  static_assert(KS % 4 == 0, "KS must be a multiple of the ring period");
  const char* wp = (const char*)W + (ntb * 64 + lane) * 16;
  const char* ap = Abuf + lane * 16;
  bf16x8 bv[4][NF];   // weight ring, 4 stages (prefetch distance 3)
  bf16x8 av[2][MF];   // A ping-pong (distance 1)
#pragma unroll
  for (int st = 0; st < 3; ++st)
#pragma unroll
    for (int nf = 0; nf < NF; ++nf)
      bv[st][nf] = *(const bf16x8*)(wp + (st * NT + nf) * 1024);
#pragma unroll
  for (int m = 0; m < MF; ++m)
    av[0][m] = *(const bf16x8*)(ap + m * KTL * 1024);
#pragma unroll 1
  for (int b = 0; b < KS / 4; ++b) {
#pragma unroll
    for (int c = 0; c < 4; ++c) {
      // A for cluster c+1 (distance 1; last body's c=3 reads 1KB past A -- LDS-safe)
#pragma unroll
      for (int m = 0; m < MF; ++m)
        av[(c + 1) & 1][m] = *(const bf16x8*)(ap + ((c + 1) + m * KTL) * 1024);
      // weights for cluster c+3 (distance 3; tail reads land in padded slack)
#pragma unroll
      for (int nf = 0; nf < NF; ++nf)
        bv[(c + 3) & 3][nf] = *(const bf16x8*)(wp + ((c + 3) * NT + nf) * 1024);
      __builtin_amdgcn_s_setprio(1);
#pragma unroll
      for (int m = 0; m < MF; ++m)
#pragma unroll
        for (int nf = 0; nf < NF; ++nf)
          acc[m][nf] = MFMA(bv[c & 3][nf], av[c & 1][m], acc[m][nf], 0, 0, 0);
      __builtin_amdgcn_s_setprio(0);
    }
    wp += 4 * NT * 1024;
    ap += 4 * 1024;
  }
}

// GEMM1: K=192 = zf_dyn (NKT=4) + zstat (NKT=2); weights NT=32, KT=6; kt pairs
// (0,1),(2,3) read zf; (4,5) read zst. MF=2 (32 rows), NF=2, ping-pong (R17-form).
__device__ __forceinline__ void gemm_g1(const char* zf, const char* zs, const bf16_t* W,
                                        int ntb, int lane, floatx4 (&acc)[2][2])
{
  const char* wp = (const char*)W + (ntb * 64 + lane) * 16;
  bf16x8 bv0[2], bv1[2];
#pragma unroll
  for (int nf = 0; nf < 2; ++nf) bv0[nf] = *(const bf16x8*)(wp + nf * 1024);
#pragma unroll 1
  for (int kt = 0; kt < 6; kt += 2) {
    const char* ab = (kt < 4) ? (zf + kt * 1024 + lane * 16)
                              : (zs + (kt - 4) * 1024 + lane * 16);
    const int  ms = (kt < 4) ? 4096 : 2048;   // mf stride (NKT*1024)
#pragma unroll
    for (int nf = 0; nf < 2; ++nf)
      bv1[nf] = *(const bf16x8*)(wp + 32 * 1024 + nf * 1024);
    bf16x8 a[2];
#pragma unroll
    for (int m = 0; m < 2; ++m) a[m] = *(const bf16x8*)(ab + m * ms);
    __builtin_amdgcn_s_setprio(1);
#pragma unroll
    for (int m = 0; m < 2; ++m)
#pragma unroll
      for (int nf = 0; nf < 2; ++nf)
        acc[m][nf] = MFMA(bv0[nf], a[m], acc[m][nf], 0, 0, 0);
    __builtin_amdgcn_s_setprio(0);
    if (kt + 2 < 6) {
#pragma unroll
      for (int nf = 0; nf < 2; ++nf)
        bv0[nf] = *(const bf16x8*)(wp + 64 * 1024 + nf * 1024);
    }
#pragma unroll
    for (int m = 0; m < 2; ++m) a[m] = *(const bf16x8*)(ab + 1024 + m * ms);
    __builtin_amdgcn_s_setprio(1);
#pragma unroll
    for (int m = 0; m < 2; ++m)
#pragma unroll
      for (int nf = 0; nf < 2; ++nf)
        acc[m][nf] = MFMA(bv1[nf], a[m], acc[m][nf], 0, 0, 0);
    __builtin_amdgcn_s_setprio(0);
    wp += 64 * 1024;
  }
}

// ------- fused kernel: 32 rows/block, 8 waves (512 thr), 2 blocks/CU -------------
// LDS/block = 78336 B -> exactly 2 blocks fit in 160 KB. launch_bounds(512,2)
// (measured R20: arch cap 128; our demand ~90 -> no spill expected).

__global__ __launch_bounds__(512, 2)
void ham_fused(const float* __restrict__ z_dyn, const float* __restrict__ z_static,
               const float* __restrict__ dtp, const float* __restrict__ ut,
               const float* __restrict__ b1, const float* __restrict__ b2,
               const bf16_t* __restrict__ W1s, const bf16_t* __restrict__ W2s,
               const bf16_t* __restrict__ W2ts, const bf16_t* __restrict__ W1ts,
               const float* __restrict__ Bc,
               float* __restrict__ z_out)
{
  __shared__ __align__(16) char bufX[32768];   // h1 -> g1 (NKT=16, mf 0..1); Bc f32 @init
  __shared__ __align__(16) char bufY[32768];   // zf (NKT=4, 8K) -> g2 (NKT=16)
  __shared__ __align__(16) char zst[4096];     // z_static frags (NKT=2, mf 0..1)
  __shared__ __align__(16) float uBs[32 * 68]; // uB, padded stride 68

  const int tid  = threadIdx.x;
  const int lane = tid & 63;
  const int w    = tid >> 6;      // 0..7
  const int lr   = lane & 15;
  const int lk   = lane >> 4;     // 0..3
  const long rb  = (long)blockIdx.x * ROWS;

  // dt is wave-uniform: pin to SGPR
  const float dtv = __builtin_bit_cast(float,
      __builtin_amdgcn_readfirstlane(__builtin_bit_cast(int, dtp[0])));
  const float hstep = dtv * 0.25f;
  const int   pcb   = ((w + 4) & 7) * 16;   // partner col base for z layout

  // ---- init: Bc -> bufX (f32), z_static -> zst (frag-linear bf16), zp regs
  for (int e = tid; e < 64 * 16; e += 512) ((float*)bufX)[e] = Bc[e];
  for (int e = tid; e < ROWS * 64; e += 512) {
    const int rr = e >> 6, cc = e & 63;
    const float v = __builtin_nontemporal_load(z_static + (rb + rr) * 64 + cc);
    const int kt = cc >> 5, lkp = (cc & 31) >> 3, j = cc & 7;
    *(bf16_t*)(zst + ((((rr >> 4) * 2 + kt) * 64) + (rr & 15) + 16 * lkp) * 16 + j * 2) = (bf16_t)v;
  }
  floatx4 zp[2];
#pragma unroll
  for (int m = 0; m < 2; ++m)
    zp[m] = __builtin_nontemporal_load(
        (const floatx4*)(z_dyn + (rb + m * 16 + lr) * 128 + pcb + lk * 4));
  __syncthreads();

  // ---- uB -> LDS (reads Bc from bufX; bufX reused after B1)
  for (int e = tid; e < ROWS * 64; e += 512) {
    const int rr = e >> 6, cc = e & 63;
    const float* ur = ut + (rb + rr) * 16;
    const float* bc = (const float*)bufX + cc * 16;
    float s = 0.f;
#pragma unroll
    for (int u = 0; u < 16; ++u) s += ur[u] * bc[u];
    uBs[rr * 68 + cc] = s;
  }

  for (int s = 0; s < 4; ++s) {
    // ---- pack zf (bufY, NKT=4) from z regs (all waves, own partner cols)
#pragma unroll
    for (int m = 0; m < 2; ++m) {
      bf16x4 o;
#pragma unroll
      for (int i = 0; i < 4; ++i) o[i] = (bf16_t)zp[m][i];
      store_frag(bufY, 4, m, pcb + lk * 4, lr, o);
    }
    __syncthreads();   // B1: zf+uBs ready; everyone past GEMM4 bufX reads (or Bc reads)

    // ---- GEMM1 -> h1 (bufX), two 256-col passes
#pragma unroll 1
    for (int p = 0; p < 2; ++p) {
      floatx4 acc[2][2] = {};
      gemm_g1(bufY, zst, W1s, p * 16 + w * 2, lane, acc);
#pragma unroll
      for (int m = 0; m < 2; ++m)
#pragma unroll
        for (int nf = 0; nf < 2; ++nf) {
          const int c0 = p * 256 + w * 32 + nf * 16 + lk * 4;
          const floatx4 b4 = *(const floatx4*)(b1 + c0);
          bf16x4 h4;
#pragma unroll
          for (int i = 0; i < 4; ++i) h4[i] = (bf16_t)softplus_f(acc[m][nf][i] + b4[i]);
          store_frag(bufX, 16, m, c0, lr, h4);
        }
    }
    __syncthreads();   // B2: h1 ready

    // ---- GEMM2 -> g2 = sigmoid(a2+b2) (bufY), two passes  [w3 folded into W2ts]
#pragma unroll 1
    for (int p = 0; p < 2; ++p) {
      floatx4 acc[2][2] = {};
      gemmP<2, 16, 16, 32, 2>(bufX, W2s, p * 16 + w * 2, lane, acc);
#pragma unroll
      for (int m = 0; m < 2; ++m)
#pragma unroll
        for (int nf = 0; nf < 2; ++nf) {
          const int c0 = p * 256 + w * 32 + nf * 16 + lk * 4;
          const floatx4 b4 = *(const floatx4*)(b2 + c0);
          bf16x4 g4;
#pragma unroll
          for (int i = 0; i < 4; ++i) g4[i] = (bf16_t)sigmoid_f(acc[m][nf][i] + b4[i]);
          store_frag(bufY, 16, m, c0, lr, g4);
        }
    }
    __syncthreads();   // B3: g2 ready

    // ---- GEMM3 -> g1 = s1 * (g2 @ (w3.W2)) (bufX), two passes
#pragma unroll 1
    for (int p = 0; p < 2; ++p) {
      floatx4 acc[2][2] = {};
      gemmP<2, 16, 16, 32, 2>(bufY, W2ts, p * 16 + w * 2, lane, acc);
#pragma unroll
      for (int m = 0; m < 2; ++m)
#pragma unroll
        for (int nf = 0; nf < 2; ++nf) {
          const int c0 = p * 256 + w * 32 + nf * 16 + lk * 4;
          const bf16x4 h4 = load_frag(bufX, 16, m, c0, lr);   // lane-private bytes
          bf16x4 g4;
#pragma unroll
          for (int i = 0; i < 4; ++i) {
            const float s1 = 1.f - __expf(-(float)h4[i]);     // sigmoid(a1) from h1
            g4[i] = (bf16_t)(s1 * acc[m][nf][i]);
          }
          store_frag(bufX, 16, m, c0, lr, g4);
        }
    }
    __syncthreads();   // B4: g1 ready

    // ---- GEMM4: dH col block w*16; z update (partner layout, in regs)
    {
      floatx4 a4[2][1] = {};
      gemmP<2, 16, 16, 8, 1>(bufX, W1ts, w, lane, a4);
#pragma unroll
      for (int m = 0; m < 2; ++m) {
        if (w < 4) {
          const float* ub = &uBs[(m * 16 + lr) * 68 + w * 16 + lk * 4];
#pragma unroll
          for (int i = 0; i < 4; ++i) zp[m][i] += hstep * (ub[i] - a4[m][0][i]);
        } else {
#pragma unroll
          for (int i = 0; i < 4; ++i) zp[m][i] += hstep * a4[m][0][i];
        }
      }
    }
    // next B1 separates GEMM4 bufX reads from GEMM1 bufX writes
  }

  // ---- final z store (nontemporal); yt handled by yt_kernel
#pragma unroll
  for (int m = 0; m < 2; ++m)
    __builtin_nontemporal_store(zp[m],
        (floatx4*)(z_out + (rb + m * 16 + lr) * 128 + pcb + lk * 4));
}

// ---------------- yt kernel: yt = z @ C^T + dt * (ut @ D^T) ----------------------
// One thread per batch row. C staged in LDS and read BROADCAST (all lanes same
// address per iteration -- conflict-free), z streamed as floatx4. (R23-verified)

__global__ __launch_bounds__(256)
void yt_kernel(const float* __restrict__ z, const float* __restrict__ ut,
               const float* __restrict__ Cm, const float* __restrict__ Dm,
               const float* __restrict__ dtp, float* __restrict__ yt_out)
{
  __shared__ float Cs[20 * 128];
  __shared__ float Ds[20 * 16];
  const int tid = threadIdx.x;
  for (int e = tid; e < 20 * 128; e += 256) Cs[e] = Cm[e];
  for (int e = tid; e < 20 * 16; e += 256) Ds[e] = Dm[e];
  const float dtv = dtp[0];
  __syncthreads();

  const long r = (long)blockIdx.x * 256 + tid;
  const float* zr = z + r * 128;
  float acc[20] = {};
#pragma unroll 4
  for (int i = 0; i < 128; i += 4) {
    const floatx4 zv = *(const floatx4*)(zr + i);
#pragma unroll
    for (int o = 0; o < 20; ++o) {
      const floatx4 cv = *(const floatx4*)(Cs + o * 128 + i);
      acc[o] += zv[0] * cv[0] + zv[1] * cv[1] + zv[2] * cv[2] + zv[3] * cv[3];
    }
  }
  float uv[16];
#pragma unroll
  for (int u = 0; u < 16; u += 4)
    *(floatx4*)(uv + u) = *(const floatx4*)(ut + r * 16 + u);
#pragma unroll
  for (int o = 0; o < 20; ++o) {
    float su = 0.f;
#pragma unroll
    for (int u = 0; u < 16; ++u) su += uv[u] * Ds[o * 16 + u];
    __builtin_nontemporal_store(acc[o] + dtv * su, yt_out + r * 20 + o);
  }
}

// ---------------- prep: kt-major fragment-linear shuffled weights ----------------
// shuf[((kt*NT + nt)*64 + ln)*8 + j] = Bt[nt*16 + (ln&15)][kt*32 + (ln>>4)*8 + j]

__global__ void prep_shuffle(const float* W1, const float* W2, const float* W3,
                             bf16_t* W1s, bf16_t* W2s, bf16_t* W2ts, bf16_t* W1ts)
{
  const long idx = (long)blockIdx.x * 256 + threadIdx.x;
  const long S1 = 98304, S2 = 262144, S3 = 262144, S4 = 65536;
  if (idx < S1) {                                   // Bt = W1 (512 x 192), NT=32, KT=6
    const long e = idx;
    const int j = (int)(e & 7), ln = (int)((e >> 3) & 63), tile = (int)(e >> 9);
    const int nt = tile & 31, kt = tile >> 5;
    const int srow = nt * 16 + (ln & 15), scol = kt * 32 + (ln >> 4) * 8 + j;
    W1s[e] = (bf16_t)W1[srow * 192 + scol];
  } else if (idx < S1 + S2) {                       // Bt = W2 (512 x 512), NT=32, KT=16
    const long e = idx - S1;
    const int j = (int)(e & 7), ln = (int)((e >> 3) & 63), tile = (int)(e >> 9);
    const int nt = tile & 31, kt = tile >> 5;
    const int srow = nt * 16 + (ln & 15), scol = kt * 32 + (ln >> 4) * 8 + j;
    W2s[e] = (bf16_t)W2[srow * 512 + scol];
  } else if (idx < S1 + S2 + S3) {                  // Bt[j][k] = W2[k][j]*w3[k], NT=32, KT=16
    const long e = idx - S1 - S2;
    const int j = (int)(e & 7), ln = (int)((e >> 3) & 63), tile = (int)(e >> 9);
    const int nt = tile & 31, kt = tile >> 5;
    const int srow = nt * 16 + (ln & 15), scol = kt * 32 + (ln >> 4) * 8 + j;
    W2ts[e] = (bf16_t)(W2[scol * 512 + srow] * W3[scol]);
  } else if (idx < S1 + S2 + S3 + S4) {             // Bt[j][k] = W1[k][j], j<128, NT=8, KT=16
    const long e = idx - S1 - S2 - S3;
    const int j = (int)(e & 7), ln = (int)((e >> 3) & 63), tile = (int)(e >> 9);
    const int nt = tile & 7, kt = tile >> 3;
    const int srow = nt * 16 + (ln & 15), scol = kt * 32 + (ln >> 4) * 8 + j;
    W1ts[e] = (bf16_t)W1[scol * 192 + srow];
  }
}

// ---------------- launch ----------------

extern "C" void kernel_launch(void* const* d_in, const int* in_sizes, int n_in,
                              void* d_out, int out_size, void* d_ws, size_t ws_size,
                              hipStream_t stream)
{
  const float* z_dyn    = (const float*)d_in[0];
  const float* z_static = (const float*)d_in[1];
  const float* dtp      = (const float*)d_in[2];
  const float* ut       = (const float*)d_in[3];
  const float* W1       = (const float*)d_in[4];
  const float* b1       = (const float*)d_in[5];
  const float* W2       = (const float*)d_in[6];
  const float* b2       = (const float*)d_in[7];
  const float* W3       = (const float*)d_in[8];
  const float* Bc       = (const float*)d_in[10];
  const float* Cm       = (const float*)d_in[11];
  const float* Dm       = (const float*)d_in[12];

  float* z_out  = (float*)d_out;            // B x 128
  float* yt_out = z_out + BATCH * 128;      // B x 20

  char* ws = (char*)d_ws;
  size_t off = 0;
  auto alloc = [&](size_t bytes) {
    char* p = ws + off;
    off = (off + bytes + 255) & ~(size_t)255;
    return p;
  };
  bf16_t* W1s  = (bf16_t*)alloc(98304 * 2);
  bf16_t* W2s  = (bf16_t*)alloc(262144 * 2);
  bf16_t* W2ts = (bf16_t*)alloc(262144 * 2);
  // +32KB slack: ring prefetch (distance 3) reads up to 3 clusters past the
  // logical end of W1ts; keep those reads in-bounds.
  bf16_t* W1ts = (bf16_t*)alloc(65536 * 2 + 32768);
  (void)ws_size; (void)in_sizes; (void)n_in; (void)out_size;

  prep_shuffle<<<2688, 256, 0, stream>>>(W1, W2, W3, W1s, W2s, W2ts, W1ts);
  ham_fused<<<(int)(BATCH / ROWS), 512, 0, stream>>>(
      z_dyn, z_static, dtp, ut, b1, b2, W1s, W2s, W2ts, W1ts, Bc, z_out);
  yt_kernel<<<(int)(BATCH / 256), 256, 0, stream>>>(z_out, ut, Cm, Dm, dtp, yt_out);
}

// Round 8
// 477.592 us; speedup vs baseline: 1.6055x; 1.1473x over previous
//
#include <hip/hip_runtime.h>
#include <hip/hip_bf16.h>
#include <math.h>

typedef __bf16 bf16_t;
typedef __bf16 bf16x8 __attribute__((ext_vector_type(8)));
typedef __bf16 bf16x4 __attribute__((ext_vector_type(4)));
typedef float floatx4 __attribute__((ext_vector_type(4)));

#define BATCH 65536L
#define ROWS 64
#define MFMA __builtin_amdgcn_mfma_f32_16x16x32_bf16

// ---------------- helpers ----------------

__device__ __forceinline__ float softplus_f(float x) {
  const float l = __logf(1.f + __expf(x));
  return (x > 15.f) ? x : l;
}
__device__ __forceinline__ float sigmoid_f(float x) {
  return __builtin_amdgcn_rcpf(1.f + __expf(-x));
}

// fragment-linear activation store/load: element block (row=mf*16+lr, cols c0..c0+3)
__device__ __forceinline__ void store_frag(char* buf, int NKT, int mf, int c0, int lr, bf16x4 v) {
  const int kt = c0 >> 5, lkp = (c0 & 31) >> 3, j0 = c0 & 7;
  *(bf16x4*)(buf + (((mf * NKT + kt) * 64) + lr + 16 * lkp) * 16 + j0 * 2) = v;
}
__device__ __forceinline__ bf16x4 load_frag(const char* buf, int NKT, int mf, int c0, int lr) {
  const int kt = c0 >> 5, lkp = (c0 & 31) >> 3, j0 = c0 & 7;
  return *(const bf16x4*)(buf + (((mf * NKT + kt) * 64) + lr + 16 * lkp) * 16 + j0 * 2);
}

// ---------------- ring-pipelined frag-linear GEMM (R22-verified body) ------------
// Weights kt-major: [kt][NT][lane][8]. A from LDS: [mf][KTL][lane][8].
// R25: body identical to R22 (88 VGPR, clean). New: callers split KT=16 GEMMs
// into two KS=8 halves and wave-parity-SWAP the half order. Theory: the two
// lockstep waves on each SIMD issue identical load bursts at identical moments
// (same code, same barrier release) -> they queue behind each other on the
// L2/LDS ports, inflating effective latency past the cluster-pair MFMA window
// (the within-GEMM ~40% MfmaUtil stall that operand-depth (R22) couldn't fix,
// because the queueing IS the latency). Starting waves on opposite K-halves
// decorrelates the burst trains. Accumulation-order change is fp32 reorder
// noise, far under tolerance (absmax bit-stable across R17-R24 reorderings).

template<int MF, int KTL, int KS, int NT, int NF>
__device__ __forceinline__ void gemmP(const char* Abuf, const bf16_t* W, int ntb,
                                      int lane, floatx4 (&acc)[MF][NF])
{
  static_assert(KS % 4 == 0, "KS must be a multiple of the ring period");
  const char* wp = (const char*)W + (ntb * 64 + lane) * 16;
  const char* ap = Abuf + lane * 16;
  bf16x8 bv[4][NF];   // weight ring, 4 stages (prefetch distance 3)
  bf16x8 av[2][MF];   // A ping-pong (distance 1)
#pragma unroll
  for (int st = 0; st < 3; ++st)
#pragma unroll
    for (int nf = 0; nf < NF; ++nf)
      bv[st][nf] = *(const bf16x8*)(wp + (st * NT + nf) * 1024);
#pragma unroll
  for (int m = 0; m < MF; ++m)
    av[0][m] = *(const bf16x8*)(ap + m * KTL * 1024);
#pragma unroll 1
  for (int b = 0; b < KS / 4; ++b) {
#pragma unroll
    for (int c = 0; c < 4; ++c) {
      // A for cluster c+1 (distance 1; tail reads stay inside the LDS window)
#pragma unroll
      for (int m = 0; m < MF; ++m)
        av[(c + 1) & 1][m] = *(const bf16x8*)(ap + ((c + 1) + m * KTL) * 1024);
      // weights for cluster c+3 (distance 3; tail reads land in allocated slack)
#pragma unroll
      for (int nf = 0; nf < NF; ++nf)
        bv[(c + 3) & 3][nf] = *(const bf16x8*)(wp + ((c + 3) * NT + nf) * 1024);
      __builtin_amdgcn_s_setprio(1);
#pragma unroll
      for (int m = 0; m < MF; ++m)
#pragma unroll
        for (int nf = 0; nf < NF; ++nf)
          acc[m][nf] = MFMA(bv[c & 3][nf], av[c & 1][m], acc[m][nf], 0, 0, 0);
      __builtin_amdgcn_s_setprio(0);
    }
    wp += 4 * NT * 1024;
    ap += 4 * 1024;
  }
}

// GEMM1: K=192 = zf_dyn (NKT=4) + zstat (NKT=2); weights NT=32, KT=6; kt pairs
// (0,1),(2,3) read zf; (4,5) read zst. MF=4, NF=2. R17-verbatim ping-pong
// (KT=6, only 14% of MFMAs -- left un-split).
__device__ __forceinline__ void gemm_g1(const char* zf, const char* zs, const bf16_t* W,
                                        int ntb, int lane, floatx4 (&acc)[4][2])
{
  const char* wp = (const char*)W + (ntb * 64 + lane) * 16;
  bf16x8 bv0[2], bv1[2];
#pragma unroll
  for (int nf = 0; nf < 2; ++nf) bv0[nf] = *(const bf16x8*)(wp + nf * 1024);
#pragma unroll 1
  for (int kt = 0; kt < 6; kt += 2) {
    const char* ab = (kt < 4) ? (zf + kt * 1024 + lane * 16)
                              : (zs + (kt - 4) * 1024 + lane * 16);
    const int  ms = (kt < 4) ? 4096 : 2048;   // mf stride (NKT*1024)
#pragma unroll
    for (int nf = 0; nf < 2; ++nf)
      bv1[nf] = *(const bf16x8*)(wp + 32 * 1024 + nf * 1024);
    bf16x8 a[4];
#pragma unroll
    for (int m = 0; m < 4; ++m) a[m] = *(const bf16x8*)(ab + m * ms);
    __builtin_amdgcn_s_setprio(1);
#pragma unroll
    for (int m = 0; m < 4; ++m)
#pragma unroll
      for (int nf = 0; nf < 2; ++nf)
        acc[m][nf] = MFMA(bv0[nf], a[m], acc[m][nf], 0, 0, 0);
    __builtin_amdgcn_s_setprio(0);
    if (kt + 2 < 6) {
#pragma unroll
      for (int nf = 0; nf < 2; ++nf)
        bv0[nf] = *(const bf16x8*)(wp + 64 * 1024 + nf * 1024);
    }
#pragma unroll
    for (int m = 0; m < 4; ++m) a[m] = *(const bf16x8*)(ab + 1024 + m * ms);
    __builtin_amdgcn_s_setprio(1);
#pragma unroll
    for (int m = 0; m < 4; ++m)
#pragma unroll
      for (int nf = 0; nf < 2; ++nf)
        acc[m][nf] = MFMA(bv1[nf], a[m], acc[m][nf], 0, 0, 0);
    __builtin_amdgcn_s_setprio(0);
    wp += 64 * 1024;
  }
}

// ---------------- fused kernel: 64 rows/block, 8 waves (512 thr), 1 block/CU ------

__global__ __launch_bounds__(512, 1)
void ham_fused(const float* __restrict__ z_dyn, const float* __restrict__ z_static,
               const float* __restrict__ dtp, const float* __restrict__ ut,
               const float* __restrict__ b1, const float* __restrict__ b2,
               const bf16_t* __restrict__ W1s, const bf16_t* __restrict__ W2s,
               const bf16_t* __restrict__ W2ts, const bf16_t* __restrict__ W1ts,
               const float* __restrict__ Bc,
               float* __restrict__ z_out)
{
  __shared__ __align__(16) char bufX[65536];   // h1 -> g1 (NKT=16, mf 0..3)
  __shared__ __align__(16) char bufY[65536];   // zf (NKT=4) -> g2 (NKT=16)
  __shared__ __align__(16) char zst[8192];     // z_static frags (NKT=2, mf 0..3)
  __shared__ __align__(16) float uBs[64 * 68]; // uB, padded stride 68

  const int tid  = threadIdx.x;
  const int lane = tid & 63;
  const int w    = tid >> 6;      // 0..7
  const int lr   = lane & 15;
  const int lk   = lane >> 4;     // 0..3
  const long rb  = (long)blockIdx.x * ROWS;
  const int  hb  = (w ^ (w >> 2)) & 1;   // K-half start parity: differs for both
                                         // plausible wave->SIMD pairings (i,i+4) and (2i,2i+1)

  // dt is wave-uniform: pin to SGPR
  const float dtv = __builtin_bit_cast(float,
      __builtin_amdgcn_readfirstlane(__builtin_bit_cast(int, dtp[0])));
  const float hstep = dtv * 0.25f;
  const int   pcb   = ((w + 4) & 7) * 16;   // partner col base for z layout

  // ---- init: Bc -> bufX (f32), z_static -> zst (frag-linear bf16), zp regs
  for (int e = tid; e < 64 * 16; e += 512) ((float*)bufX)[e] = Bc[e];
  for (int e = tid; e < ROWS * 64; e += 512) {
    const int rr = e >> 6, cc = e & 63;
    const float v = __builtin_nontemporal_load(z_static + (rb + rr) * 64 + cc);
    const int kt = cc >> 5, lkp = (cc & 31) >> 3, j = cc & 7;
    *(bf16_t*)(zst + ((((rr >> 4) * 2 + kt) * 64) + (rr & 15) + 16 * lkp) * 16 + j * 2) = (bf16_t)v;
  }
  floatx4 zp[4];
#pragma unroll
  for (int m = 0; m < 4; ++m)
    zp[m] = __builtin_nontemporal_load(
        (const floatx4*)(z_dyn + (rb + m * 16 + lr) * 128 + pcb + lk * 4));
  __syncthreads();

  // ---- uB -> LDS (reads Bc from bufX; bufX reused after B1)
  for (int e = tid; e < ROWS * 64; e += 512) {
    const int rr = e >> 6, cc = e & 63;
    const float* ur = ut + (rb + rr) * 16;
    const float* bc = (const float*)bufX + cc * 16;
    float s = 0.f;
#pragma unroll
    for (int u = 0; u < 16; ++u) s += ur[u] * bc[u];
    uBs[rr * 68 + cc] = s;
  }

  for (int s = 0; s < 4; ++s) {
    // ---- pack zf (bufY, NKT=4) from z regs (all 4 row-frags, own partner cols)
#pragma unroll
    for (int m = 0; m < 4; ++m) {
      bf16x4 o;
#pragma unroll
      for (int i = 0; i < 4; ++i) o[i] = (bf16_t)zp[m][i];
      store_frag(bufY, 4, m, pcb + lk * 4, lr, o);
    }
    __syncthreads();   // B1: zf+uBs ready; everyone past GEMM4/bufX reads (or Bc reads)

    // ---- GEMM1 -> h1 (bufX), two 256-col passes
#pragma unroll 1
    for (int p = 0; p < 2; ++p) {
      floatx4 acc[4][2] = {};
      gemm_g1(bufY, zst, W1s, p * 16 + w * 2, lane, acc);
#pragma unroll
      for (int m = 0; m < 4; ++m)
#pragma unroll
        for (int nf = 0; nf < 2; ++nf) {
          const int c0 = p * 256 + w * 32 + nf * 16 + lk * 4;
          const floatx4 b4 = *(const floatx4*)(b1 + c0);
          bf16x4 h4;
#pragma unroll
          for (int i = 0; i < 4; ++i) h4[i] = (bf16_t)softplus_f(acc[m][nf][i] + b4[i]);
          store_frag(bufX, 16, m, c0, lr, h4);
        }
    }
    __syncthreads();   // B2: h1 ready

    // ---- GEMM2 -> g2 = sigmoid(a2+b2) (bufY), two passes, K-halves desynced
#pragma unroll 1
    for (int p = 0; p < 2; ++p) {
      floatx4 acc[4][2] = {};
      gemmP<4, 16, 8, 32, 2>(bufX + hb * 8192, W2s + hb * 131072,
                             p * 16 + w * 2, lane, acc);
      gemmP<4, 16, 8, 32, 2>(bufX + (hb ^ 1) * 8192, W2s + (hb ^ 1) * 131072,
                             p * 16 + w * 2, lane, acc);
#pragma unroll
      for (int m = 0; m < 4; ++m)
#pragma unroll
        for (int nf = 0; nf < 2; ++nf) {
          const int c0 = p * 256 + w * 32 + nf * 16 + lk * 4;
          const floatx4 b4 = *(const floatx4*)(b2 + c0);
          bf16x4 g4;
#pragma unroll
          for (int i = 0; i < 4; ++i) g4[i] = (bf16_t)sigmoid_f(acc[m][nf][i] + b4[i]);
          store_frag(bufY, 16, m, c0, lr, g4);
        }
    }
    __syncthreads();   // B3: g2 ready

    // ---- GEMM3 -> g1 = s1 * (g2 @ (w3.W2)) (bufX), two passes, K-halves desynced
#pragma unroll 1
    for (int p = 0; p < 2; ++p) {
      floatx4 acc[4][2] = {};
      gemmP<4, 16, 8, 32, 2>(bufY + hb * 8192, W2ts + hb * 131072,
                             p * 16 + w * 2, lane, acc);
      gemmP<4, 16, 8, 32, 2>(bufY + (hb ^ 1) * 8192, W2ts + (hb ^ 1) * 131072,
                             p * 16 + w * 2, lane, acc);
#pragma unroll
      for (int m = 0; m < 4; ++m)
#pragma unroll
        for (int nf = 0; nf < 2; ++nf) {
          const int c0 = p * 256 + w * 32 + nf * 16 + lk * 4;
          const bf16x4 h4 = load_frag(bufX, 16, m, c0, lr);   // lane-private bytes
          bf16x4 g4;
#pragma unroll
          for (int i = 0; i < 4; ++i) {
            const float s1 = 1.f - __expf(-(float)h4[i]);     // sigmoid(a1) from h1
            g4[i] = (bf16_t)(s1 * acc[m][nf][i]);
          }
          store_frag(bufX, 16, m, c0, lr, g4);
        }
    }
    __syncthreads();   // B4: g1 ready

    // ---- GEMM4: dH col block w*16; K-halves desynced; z update (in regs)
    {
      floatx4 a4[4][1] = {};
      gemmP<4, 16, 8, 8, 1>(bufX + hb * 8192, W1ts + hb * 32768, w, lane, a4);
      gemmP<4, 16, 8, 8, 1>(bufX + (hb ^ 1) * 8192, W1ts + (hb ^ 1) * 32768, w, lane, a4);
#pragma unroll
      for (int m = 0; m < 4; ++m) {
        if (w < 4) {
          const float* ub = &uBs[(m * 16 + lr) * 68 + w * 16 + lk * 4];
#pragma unroll
          for (int i = 0; i < 4; ++i) zp[m][i] += hstep * (ub[i] - a4[m][0][i]);
        } else {
#pragma unroll
          for (int i = 0; i < 4; ++i) zp[m][i] += hstep * a4[m][0][i];
        }
      }
    }
    // next B1 separates GEMM4 bufX reads from GEMM1 bufX writes
  }

  // ---- final z store (nontemporal); yt handled by yt_kernel
#pragma unroll
  for (int m = 0; m < 4; ++m)
    __builtin_nontemporal_store(zp[m],
        (floatx4*)(z_out + (rb + m * 16 + lr) * 128 + pcb + lk * 4));
}

// ---------------- yt kernel: yt = z @ C^T + dt * (ut @ D^T) ----------------------
// One thread per batch row. C staged in LDS and read BROADCAST (all lanes same
// address per iteration -- conflict-free), z streamed as floatx4. (R23/R24-verified)

__global__ __launch_bounds__(256)
void yt_kernel(const float* __restrict__ z, const float* __restrict__ ut,
               const float* __restrict__ Cm, const float* __restrict__ Dm,
               const float* __restrict__ dtp, float* __restrict__ yt_out)
{
  __shared__ float Cs[20 * 128];
  __shared__ float Ds[20 * 16];
  const int tid = threadIdx.x;
  for (int e = tid; e < 20 * 128; e += 256) Cs[e] = Cm[e];
  for (int e = tid; e < 20 * 16; e += 256) Ds[e] = Dm[e];
  const float dtv = dtp[0];
  __syncthreads();

  const long r = (long)blockIdx.x * 256 + tid;
  const float* zr = z + r * 128;
  float acc[20] = {};
#pragma unroll 4
  for (int i = 0; i < 128; i += 4) {
    const floatx4 zv = *(const floatx4*)(zr + i);
#pragma unroll
    for (int o = 0; o < 20; ++o) {
      const floatx4 cv = *(const floatx4*)(Cs + o * 128 + i);
      acc[o] += zv[0] * cv[0] + zv[1] * cv[1] + zv[2] * cv[2] + zv[3] * cv[3];
    }
  }
  float uv[16];
#pragma unroll
  for (int u = 0; u < 16; u += 4)
    *(floatx4*)(uv + u) = *(const floatx4*)(ut + r * 16 + u);
#pragma unroll
  for (int o = 0; o < 20; ++o) {
    float su = 0.f;
#pragma unroll
    for (int u = 0; u < 16; ++u) su += uv[u] * Ds[o * 16 + u];
    __builtin_nontemporal_store(acc[o] + dtv * su, yt_out + r * 20 + o);
  }
}

// ---------------- prep: kt-major fragment-linear shuffled weights ----------------
// shuf[((kt*NT + nt)*64 + ln)*8 + j] = Bt[nt*16 + (ln&15)][kt*32 + (ln>>4)*8 + j]

__global__ void prep_shuffle(const float* W1, const float* W2, const float* W3,
                             bf16_t* W1s, bf16_t* W2s, bf16_t* W2ts, bf16_t* W1ts)
{
  const long idx = (long)blockIdx.x * 256 + threadIdx.x;
  const long S1 = 98304, S2 = 262144, S3 = 262144, S4 = 65536;
  if (idx < S1) {                                   // Bt = W1 (512 x 192), NT=32, KT=6
    const long e = idx;
    const int j = (int)(e & 7), ln = (int)((e >> 3) & 63), tile = (int)(e >> 9);
    const int nt = tile & 31, kt = tile >> 5;
    const int srow = nt * 16 + (ln & 15), scol = kt * 32 + (ln >> 4) * 8 + j;
    W1s[e] = (bf16_t)W1[srow * 192 + scol];
  } else if (idx < S1 + S2) {                       // Bt = W2 (512 x 512), NT=32, KT=16
    const long e = idx - S1;
    const int j = (int)(e & 7), ln = (int)((e >> 3) & 63), tile = (int)(e >> 9);
    const int nt = tile & 31, kt = tile >> 5;
    const int srow = nt * 16 + (ln & 15), scol = kt * 32 + (ln >> 4) * 8 + j;
    W2s[e] = (bf16_t)W2[srow * 512 + scol];
  } else if (idx < S1 + S2 + S3) {                  // Bt[j][k] = W2[k][j]*w3[k], NT=32, KT=16
    const long e = idx - S1 - S2;
    const int j = (int)(e & 7), ln = (int)((e >> 3) & 63), tile = (int)(e >> 9);
    const int nt = tile & 31, kt = tile >> 5;
    const int srow = nt * 16 + (ln & 15), scol = kt * 32 + (ln >> 4) * 8 + j;
    W2ts[e] = (bf16_t)(W2[scol * 512 + srow] * W3[scol]);
  } else if (idx < S1 + S2 + S3 + S4) {             // Bt[j][k] = W1[k][j], j<128, NT=8, KT=16
    const long e = idx - S1 - S2 - S3;
    const int j = (int)(e & 7), ln = (int)((e >> 3) & 63), tile = (int)(e >> 9);
    const int nt = tile & 7, kt = tile >> 3;
    const int srow = nt * 16 + (ln & 15), scol = kt * 32 + (ln >> 4) * 8 + j;
    W1ts[e] = (bf16_t)W1[scol * 192 + srow];
  }
}

// ---------------- launch ----------------

extern "C" void kernel_launch(void* const* d_in, const int* in_sizes, int n_in,
                              void* d_out, int out_size, void* d_ws, size_t ws_size,
                              hipStream_t stream)
{
  const float* z_dyn    = (const float*)d_in[0];
  const float* z_static = (const float*)d_in[1];
  const float* dtp      = (const float*)d_in[2];
  const float* ut       = (const float*)d_in[3];
  const float* W1       = (const float*)d_in[4];
  const float* b1       = (const float*)d_in[5];
  const float* W2       = (const float*)d_in[6];
  const float* b2       = (const float*)d_in[7];
  const float* W3       = (const float*)d_in[8];
  const float* Bc       = (const float*)d_in[10];
  const float* Cm       = (const float*)d_in[11];
  const float* Dm       = (const float*)d_in[12];

  float* z_out  = (float*)d_out;            // B x 128
  float* yt_out = z_out + BATCH * 128;      // B x 20

  char* ws = (char*)d_ws;
  size_t off = 0;
  auto alloc = [&](size_t bytes) {
    char* p = ws + off;
    off = (off + bytes + 255) & ~(size_t)255;
    return p;
  };
  bf16_t* W1s  = (bf16_t*)alloc(98304 * 2);
  bf16_t* W2s  = (bf16_t*)alloc(262144 * 2);
  bf16_t* W2ts = (bf16_t*)alloc(262144 * 2);
  // +32KB slack: ring prefetch (distance 3) reads up to 3 kt (24KB) past the
  // logical end of W1ts' second K-half; keep those reads in-bounds.
  bf16_t* W1ts = (bf16_t*)alloc(65536 * 2 + 32768);
  (void)ws_size; (void)in_sizes; (void)n_in; (void)out_size;

  prep_shuffle<<<2688, 256, 0, stream>>>(W1, W2, W3, W1s, W2s, W2ts, W1ts);
  ham_fused<<<(int)(BATCH / ROWS), 512, 0, stream>>>(
      z_dyn, z_static, dtp, ut, b1, b2, W1s, W2s, W2ts, W1ts, Bc, z_out);
  yt_kernel<<<(int)(BATCH / 256), 256, 0, stream>>>(z_out, ut, Cm, Dm, dtp, yt_out);
}